// Round 8
// baseline (4061.492 us; speedup 1.0000x reference)
//
#include <hip/hip_runtime.h>
#include <hip/hip_bf16.h>

#define Bsz 4096
#define Dsz 256
#define Hsz 512
#define Tsz 45

typedef __attribute__((ext_vector_type(8))) short short8;
typedef __attribute__((ext_vector_type(4))) float f32x4;
typedef __attribute__((ext_vector_type(4))) unsigned short us4;
using bf16 = __hip_bfloat16;

__device__ __forceinline__ float sigf(float x)   { return 1.0f / (1.0f + __expf(-x)); }
__device__ __forceinline__ float tanhft(float x) { return 1.0f - 2.0f / (__expf(2.0f * x) + 1.0f); }
__device__ __forceinline__ float b2f(unsigned short u) { return __uint_as_float((unsigned)u << 16); }

__device__ __forceinline__ void gload16(const void* g, void* l) {
    __builtin_amdgcn_global_load_lds((const __attribute__((address_space(1))) void*)g,
                                     (__attribute__((address_space(3))) void*)l, 16, 0, 0);
}

// ---------------------------------------------------------------------------
// Weight convert / transpose (one-shot).
// ---------------------------------------------------------------------------
__global__ void k_conv(const float* __restrict__ ef,   const float* __restrict__ ctx,
                       const float* __restrict__ Whi,  const float* __restrict__ Wci,
                       const float* __restrict__ Wih0, const float* __restrict__ Whh0,
                       const float* __restrict__ Wih1, const float* __restrict__ Whh1,
                       const float* __restrict__ Wo1,  const float* __restrict__ Wg1,
                       bf16* __restrict__ efb,  bf16* __restrict__ ctxb,
                       bf16* __restrict__ Wit,  bf16* __restrict__ Wt0,
                       bf16* __restrict__ Wt1,  bf16* __restrict__ Wo1t,
                       bf16* __restrict__ Wg1t)
{
    size_t tid = (size_t)blockIdx.x * blockDim.x + threadIdx.x;
    size_t gsz = (size_t)gridDim.x * blockDim.x;
    for (size_t i = tid; i < (size_t)Bsz * Dsz; i += gsz) {
        efb[i]  = __float2bfloat16(ef[i]);
        ctxb[i] = __float2bfloat16(ctx[i]);
    }
    for (size_t i = tid; i < 2048ull * 512; i += gsz) {     // Wt0[n][k] = W_hh0[k][n]
        size_t n = i >> 9, k = i & 511;
        Wt0[i] = __float2bfloat16(Whh0[k * 2048 + n]);
    }
    for (size_t i = tid; i < 2048ull * 1024; i += gsz) {    // Wt1[n][k] = [W_ih1; W_hh1][k][n]
        size_t n = i >> 10, k = i & 1023;
        Wt1[i] = __float2bfloat16(k < 512 ? Wih1[k * 2048 + n] : Whh1[(k - 512) * 2048 + n]);
    }
    for (size_t i = tid; i < 32ull * 512; i += gsz) {       // Wo1t/Wg1t[c][k]
        size_t c = i >> 9, k = i & 511;
        Wo1t[i] = __float2bfloat16(Wo1[k * 32 + c]);
        Wg1t[i] = __float2bfloat16(Wg1[k * 32 + c]);
    }
    for (size_t i = tid; i < 4096ull * 256; i += gsz) {     // Wit[n][k]: [Wh_init;Wc_init;W_ih0[1:]]^T
        size_t n = i >> 8, k = i & 255;
        float v = (n < 1024) ? Whi[k * 1024 + n]
                : (n < 2048) ? Wci[k * 1024 + (n - 1024)]
                             : Wih0[(1 + k) * 2048 + (n - 2048)];
        Wit[i] = __float2bfloat16(v);
    }
}

// ---------------------------------------------------------------------------
// Init GEMM: [h_init | c_init | ctx_gates]. ctx_gates stored [b][j][4 gates].
// ---------------------------------------------------------------------------
__global__ void __launch_bounds__(256)
k_init(const bf16* __restrict__ efb, const bf16* __restrict__ ctxb,
       const bf16* __restrict__ Wit,
       const float* __restrict__ bh,  const float* __restrict__ bc,
       const float* __restrict__ bi0, const float* __restrict__ bh0,
       bf16* __restrict__ h0, bf16* __restrict__ h1,
       float* __restrict__ c0, float* __restrict__ c1,
       bf16* __restrict__ ctxg)
{
    const int t = threadIdx.x, lane = t & 63, w = t >> 6;
    const int wr = w >> 1, wc = w & 1;
    const int lq = lane >> 4, ln = lane & 15;
    const int m0 = blockIdx.x * 128, n0 = blockIdx.y * 64;
    const bf16* A = (n0 < 2048) ? efb : ctxb;

    f32x4 zero = {0.f, 0.f, 0.f, 0.f};
    f32x4 acc[4][2];
#pragma unroll
    for (int r = 0; r < 4; ++r)
#pragma unroll
        for (int c = 0; c < 2; ++c) acc[r][c] = zero;

    for (int k0 = 0; k0 < 256; k0 += 32) {
        short8 af[4];
#pragma unroll
        for (int r = 0; r < 4; ++r)
            af[r] = *(const short8*)(A + (size_t)(m0 + wr * 64 + r * 16 + ln) * 256 + k0 + lq * 8);
#pragma unroll
        for (int c = 0; c < 2; ++c) {
            short8 bv = *(const short8*)(Wit + (size_t)(n0 + wc * 32 + c * 16 + ln) * 256 + k0 + lq * 8);
#pragma unroll
            for (int r = 0; r < 4; ++r)
                acc[r][c] = __builtin_amdgcn_mfma_f32_16x16x32_bf16(af[r], bv, acc[r][c], 0, 0, 0);
        }
    }
#pragma unroll
    for (int r = 0; r < 4; ++r)
#pragma unroll
        for (int c = 0; c < 2; ++c)
#pragma unroll
            for (int e = 0; e < 4; ++e) {
                int b = m0 + wr * 64 + r * 16 + lq * 4 + e;
                int n = n0 + wc * 32 + c * 16 + ln;
                float v = acc[r][c][e];
                if (n < 1024) {
                    v += bh[n];
                    if (n < 512) h0[(size_t)b * 512 + n]       = __float2bfloat16(v);
                    else         h1[(size_t)b * 512 + n - 512] = __float2bfloat16(v);
                } else if (n < 2048) {
                    int m = n - 1024; v += bc[m];
                    if (m < 512) c0[(size_t)b * 512 + m]       = v;
                    else         c1[(size_t)b * 512 + m - 512] = v;
                } else {
                    int j = n - 2048;
                    ctxg[(size_t)b * 2048 + (j & 511) * 4 + (j >> 9)] =
                        __float2bfloat16(v + bi0[j] + bh0[j]);
                }
            }
}

// ---------------------------------------------------------------------------
// intent head kernel: 128 rows per WG, writes strided out column and iws.
// ---------------------------------------------------------------------------
__global__ void __launch_bounds__(256)
k_intent(const bf16* __restrict__ h, const bf16* __restrict__ W1t,
         const float* __restrict__ bias1, const float* __restrict__ W2,
         const float* __restrict__ bias2,
         float* __restrict__ outp, int ostride, float* __restrict__ iws)
{
    const int t = threadIdx.x, lane = t & 63, w = t >> 6;
    const int lq = lane >> 4, ln = lane & 15;
    const int m0 = blockIdx.x * 128;
    f32x4 zero = {0.f, 0.f, 0.f, 0.f};
    f32x4 acc[2][2];
#pragma unroll
    for (int r = 0; r < 2; ++r)
#pragma unroll
        for (int c = 0; c < 2; ++c) acc[r][c] = zero;

#pragma unroll
    for (int k0 = 0; k0 < 512; k0 += 32) {
        short8 av[2], bv[2];
#pragma unroll
        for (int r = 0; r < 2; ++r)
            av[r] = *(const short8*)(h + (size_t)(m0 + w * 32 + r * 16 + ln) * 512 + k0 + lq * 8);
#pragma unroll
        for (int c = 0; c < 2; ++c)
            bv[c] = *(const short8*)(W1t + (size_t)(c * 16 + ln) * 512 + k0 + lq * 8);
#pragma unroll
        for (int r = 0; r < 2; ++r)
#pragma unroll
            for (int c = 0; c < 2; ++c)
                acc[r][c] = __builtin_amdgcn_mfma_f32_16x16x32_bf16(av[r], bv[c], acc[r][c], 0, 0, 0);
    }
#pragma unroll
    for (int r = 0; r < 2; ++r)
#pragma unroll
        for (int e = 0; e < 4; ++e) {
            float v = 0.f;
#pragma unroll
            for (int c = 0; c < 2; ++c) {
                int col = c * 16 + ln;
                v += fmaxf(acc[r][c][e] + bias1[col], 0.f) * W2[col];
            }
            v += __shfl_xor(v, 1);
            v += __shfl_xor(v, 2);
            v += __shfl_xor(v, 4);
            v += __shfl_xor(v, 8);
            int row = w * 32 + r * 16 + lq * 4 + e;          // 0..127
            if (ln == 0) {
                float p = sigf(v + bias2[0]);
                outp[(size_t)(m0 + row) * ostride] = p;
                if (iws) iws[m0 + row] = p;
            }
        }
}

// ---------------------------------------------------------------------------
// Staging: one BK=32 tile into a 32 KB ring buffer.
// A: 256 rows x 32k (16 KB) at buf+0; B: 256 brows (4g x 64n) x 32k at +16 KB.
// 4 chunks/row, swizzle slot = kc ^ ((row>>1)&3) on the GLOBAL side.
// 512 threads: 2 A-chunks + 2 B-chunks per thread.
// ---------------------------------------------------------------------------
template <int L0>
__device__ __forceinline__ void stage(const bf16* __restrict__ hA, const bf16* __restrict__ hB,
                                      const bf16* __restrict__ Wt,
                                      int m0, int j0, int k0, char* buf, int t)
{
    constexpr int KW = L0 ? 512 : 1024;
#pragma unroll
    for (int i = 0; i < 2; ++i) {
        int f = i * 512 + t;
        int row = f >> 2, slot = f & 3;
        int kk = k0 + ((slot ^ ((row >> 1) & 3)) << 3);
        const bf16* src;
        if (L0) src = hA + (size_t)(m0 + row) * Hsz + kk;
        else    src = (kk < 512) ? hA + (size_t)(m0 + row) * Hsz + kk
                                 : hB + (size_t)(m0 + row) * Hsz + (kk - 512);
        gload16(src, buf + (size_t)f * 16);
    }
#pragma unroll
    for (int i = 0; i < 2; ++i) {
        int f = i * 512 + t;
        int brow = f >> 2, slot = f & 3;               // brow = g*64 + n
        int kc = slot ^ ((brow >> 1) & 3);
        gload16(Wt + (size_t)((brow >> 6) * 512 + j0 + (brow & 63)) * KW + k0 + kc * 8,
                buf + 16384 + (size_t)f * 16);
    }
}

// one BK=32 tile of MFMA work per wave: 4 gates x 8 row-frags = 32 MFMA
__device__ __forceinline__ void mfma_tile(const char* buf,
                                          int wr, int wcg, int lq, int ln,
                                          f32x4 (&acc)[4][8])
{
    const bf16* Ab = (const bf16*)buf;
    const bf16* Bb = (const bf16*)(buf + 16384);
    short8 af[8], bfr[4];
#pragma unroll
    for (int r = 0; r < 8; ++r) {
        int row = wr * 128 + r * 16 + ln;
        int slot = lq ^ ((row >> 1) & 3);
        af[r] = *(const short8*)(Ab + ((size_t)row * 4 + slot) * 8);
    }
#pragma unroll
    for (int g = 0; g < 4; ++g) {
        int brow = g * 64 + wcg * 16 + ln;
        int slot = lq ^ ((brow >> 1) & 3);
        bfr[g] = *(const short8*)(Bb + ((size_t)brow * 4 + slot) * 8);
    }
#pragma unroll
    for (int g = 0; g < 4; ++g)
#pragma unroll
        for (int r = 0; r < 8; ++r)
            acc[g][r] = __builtin_amdgcn_mfma_f32_16x16x32_bf16(af[r], bfr[g], acc[g][r], 0, 0, 0);
}

#define WAIT_VM(N) asm volatile("s_waitcnt vmcnt(" #N ")" ::: "memory")

// ---------------------------------------------------------------------------
// Fused gates GEMM + LSTM cell. 256 rows x 64 gate-cols x 4 gates per WG
// (512 threads, 8 waves: wr = w>>2 row-half, wcg = w&3 col-quarter).
// Grid 128 = 16 mblk x 8 jblk -> halves both A and W delivered bytes vs 128².
// Ring-4 LDS (4 x 32 KB), depth-3, counted vmcnt, one raw barrier per tile.
// ---------------------------------------------------------------------------
template <int L0>
__global__ void __launch_bounds__(512)
k_gates(const bf16* __restrict__ hA, const bf16* __restrict__ hB,
        const bf16* __restrict__ Wt,
        const bf16* __restrict__ ctxg, const float* __restrict__ intent_src,
        const float* __restrict__ w0row,
        const float* __restrict__ b1, const float* __restrict__ b2,
        float* __restrict__ cbuf, bf16* __restrict__ hout)
{
    constexpr int KW = L0 ? 512 : 1024;
    constexpr int NT = KW / 32;
    __shared__ __align__(16) char lds[131072];         // 4 ring buffers x 32 KB

    const int t = threadIdx.x, lane = t & 63, w = t >> 6;
    const int wr = w >> 2, wcg = w & 3, lq = lane >> 4, ln = lane & 15;
    const int bid = blockIdx.x;
    const int xcd = bid & 7, rem = bid >> 3;
    const int mblk = xcd * 2 + (rem & 1), jblk = rem >> 1;   // mblk-major per XCD
    const int m0 = mblk * 256, j0 = jblk * 64;

    // prologue: 3 stage tiles in flight (12 loads/thread)
    stage<L0>(hA, hB, Wt, m0, j0, 0,  lds,          t);
    stage<L0>(hA, hB, Wt, m0, j0, 32, lds + 32768,  t);
    stage<L0>(hA, hB, Wt, m0, j0, 64, lds + 65536,  t);

    f32x4 zero = {0.f, 0.f, 0.f, 0.f};
    f32x4 acc[4][8];
#pragma unroll
    for (int g = 0; g < 4; ++g)
#pragma unroll
        for (int r = 0; r < 8; ++r) acc[g][r] = zero;

    // main loop: wait own tile-kt loads (8 younger stay in flight), barrier
    // (=> buffer complete across waves), compute, issue stage kt+3.
#pragma unroll 4
    for (int kt = 0; kt < NT - 3; ++kt) {
        WAIT_VM(8);
        __builtin_amdgcn_s_barrier();
        mfma_tile(lds + (size_t)(kt & 3) * 32768, wr, wcg, lq, ln, acc);
        stage<L0>(hA, hB, Wt, m0, j0, (kt + 3) * 32, lds + (size_t)((kt + 3) & 3) * 32768, t);
    }
    WAIT_VM(8);
    __builtin_amdgcn_s_barrier();
    mfma_tile(lds + (size_t)((NT - 3) & 3) * 32768, wr, wcg, lq, ln, acc);
    WAIT_VM(4);
    __builtin_amdgcn_s_barrier();
    mfma_tile(lds + (size_t)((NT - 2) & 3) * 32768, wr, wcg, lq, ln, acc);
    WAIT_VM(0);
    __builtin_amdgcn_s_barrier();
    mfma_tile(lds + (size_t)((NT - 1) & 3) * 32768, wr, wcg, lq, ln, acc);

    // ---- fused LSTM cell epilogue. C/D frag: col=lane&15, row=(lane>>4)*4+reg
    const int jl = j0 + wcg * 16 + ln;
    float addc[4];
#pragma unroll
    for (int g = 0; g < 4; ++g)
        addc[g] = L0 ? w0row[g * 512 + jl] : (b1[g * 512 + jl] + b2[g * 512 + jl]);

#pragma unroll
    for (int r = 0; r < 8; ++r)
#pragma unroll
        for (int e = 0; e < 4; ++e) {
            int b = m0 + wr * 128 + r * 16 + lq * 4 + e;
            float pre[4];
#pragma unroll
            for (int g = 0; g < 4; ++g) pre[g] = acc[g][r][e];
            if (L0) {
                float it = intent_src[b];
                us4 cg = *(const us4*)((const unsigned short*)ctxg + (size_t)b * 2048 + jl * 4);
#pragma unroll
                for (int g = 0; g < 4; ++g) pre[g] += b2f(cg[g]) + it * addc[g];
            } else {
#pragma unroll
                for (int g = 0; g < 4; ++g) pre[g] += addc[g];
            }
            float ig = sigf(pre[0]), fg = sigf(pre[1]);
            float gg = tanhft(pre[2]), og = sigf(pre[3]);
            size_t idxb = (size_t)b * Hsz + jl;
            float cn = fg * cbuf[idxb] + ig * gg;
            cbuf[idxb] = cn;
            hout[idxb] = __float2bfloat16(og * tanhft(cn));
        }
}

// ---------------------------------------------------------------------------
extern "C" void kernel_launch(void* const* d_in, const int* in_sizes, int n_in,
                              void* d_out, int out_size, void* d_ws, size_t ws_size,
                              hipStream_t stream)
{
    const float* ef   = (const float*)d_in[0];
    const float* ctx  = (const float*)d_in[1];
    const float* ii   = (const float*)d_in[2];
    const float* Whi  = (const float*)d_in[3];
    const float* bh   = (const float*)d_in[4];
    const float* Wci  = (const float*)d_in[5];
    const float* bc   = (const float*)d_in[6];
    const float* Wih0 = (const float*)d_in[7];
    const float* Whh0 = (const float*)d_in[8];
    const float* bi0  = (const float*)d_in[9];
    const float* bh0  = (const float*)d_in[10];
    const float* Wih1 = (const float*)d_in[11];
    const float* Whh1 = (const float*)d_in[12];
    const float* bi1  = (const float*)d_in[13];
    const float* bh1  = (const float*)d_in[14];
    const float* Wo1  = (const float*)d_in[15];
    const float* bo1  = (const float*)d_in[16];
    const float* Wo2  = (const float*)d_in[17];
    const float* bo2  = (const float*)d_in[18];
    const float* Wg1  = (const float*)d_in[19];
    const float* bg1  = (const float*)d_in[20];
    const float* Wg2  = (const float*)d_in[21];
    const float* bg2  = (const float*)d_in[22];
    float* out = (float*)d_out;

    char* ws = (char*)d_ws;
    size_t off = 0;
    auto take = [&](size_t bytes) -> char* {
        char* pp = ws + off;
        off += (bytes + 255) & ~(size_t)255;
        return pp;
    };
    bf16* Wt0    = (bf16*)take(2048ull * 512 * 2);
    bf16* Wt1    = (bf16*)take(2048ull * 1024 * 2);
    bf16* Wo1t   = (bf16*)take(32ull * 512 * 2);
    bf16* Wg1t   = (bf16*)take(32ull * 512 * 2);
    bf16* Wit    = (bf16*)take(4096ull * 256 * 2);
    bf16* efb    = (bf16*)take((size_t)Bsz * Dsz * 2);
    bf16* ctxb   = (bf16*)take((size_t)Bsz * Dsz * 2);
    bf16* h0x    = (bf16*)take((size_t)Bsz * Hsz * 2);
    bf16* h0y    = (bf16*)take((size_t)Bsz * Hsz * 2);
    bf16* h1x    = (bf16*)take((size_t)Bsz * Hsz * 2);
    bf16* h1y    = (bf16*)take((size_t)Bsz * Hsz * 2);
    float* c0    = (float*)take((size_t)Bsz * Hsz * 4);
    float* c1    = (float*)take((size_t)Bsz * Hsz * 4);
    bf16* ctxg   = (bf16*)take((size_t)Bsz * 2048 * 2);
    float* iws   = (float*)take((size_t)Bsz * 4);
    (void)ws_size; (void)in_sizes; (void)n_in; (void)out_size;

    k_conv<<<2048, 256, 0, stream>>>(ef, ctx, Whi, Wci, Wih0, Whh0, Wih1, Whh1, Wo1, Wg1,
                                     efb, ctxb, Wit, Wt0, Wt1, Wo1t, Wg1t);
    k_init<<<dim3(32, 64), 256, 0, stream>>>(efb, ctxb, Wit, bh, bc, bi0, bh0,
                                             h0x, h1x, c0, c1, ctxg);

    for (int s = 0; s < Tsz; ++s) {
        int p = s & 1;
        const bf16* h0in  = p ? h0y : h0x;
        bf16*       h0out = p ? h0x : h0y;
        const bf16* h1in  = p ? h1y : h1x;
        bf16*       h1out = p ? h1x : h1y;
        const float* isrc = (s == 0) ? ii : iws;
        k_gates<1><<<128, 512, 0, stream>>>(
            h0in, nullptr, Wt0, ctxg, isrc, Wih0, nullptr, nullptr, c0, h0out);
        k_gates<0><<<128, 512, 0, stream>>>(
            h0out, h1in, Wt1, nullptr, nullptr, nullptr, bi1, bh1, c1, h1out);
        k_intent<<<32, 256, 0, stream>>>(h1out, Wo1t, bo1, Wo2, bo2, out + s, Tsz, iws);
    }
    // final h1 = h1y (s=44 even); global head
    k_intent<<<32, 256, 0, stream>>>(h1y, Wg1t, bg1, Wg2, bg2,
                                     out + (size_t)Bsz * Tsz, 1, nullptr);
}

// Round 9
// 2680.870 us; speedup vs baseline: 1.5150x; 1.5150x over previous
//
#include <hip/hip_runtime.h>
#include <hip/hip_bf16.h>

#define Bsz 4096
#define Dsz 256
#define Hsz 512
#define Tsz 45

typedef __attribute__((ext_vector_type(8))) short short8;
typedef __attribute__((ext_vector_type(4))) float f32x4;
typedef __attribute__((ext_vector_type(4))) unsigned short us4;
using bf16 = __hip_bfloat16;
using u8 = unsigned char;

__device__ __forceinline__ float sigf(float x)   { return 1.0f / (1.0f + __expf(-x)); }
__device__ __forceinline__ float tanhft(float x) { return 1.0f - 2.0f / (__expf(2.0f * x) + 1.0f); }
__device__ __forceinline__ float b2f(unsigned short u) { return __uint_as_float((unsigned)u << 16); }
__device__ __forceinline__ u8 f2fp8(float v) {
    int p = __builtin_amdgcn_cvt_pk_fp8_f32(v, v, 0, false);
    return (u8)(p & 0xff);
}

__device__ __forceinline__ void gload16(const void* g, void* l) {
    __builtin_amdgcn_global_load_lds((const __attribute__((address_space(1))) void*)g,
                                     (__attribute__((address_space(3))) void*)l, 16, 0, 0);
}

// ---------------------------------------------------------------------------
// Weight convert (one-shot): bf16 for init GEMM, fp8 e4m3 for recurrent GEMMs.
// Wt layouts (N, K) so B-fragment = contiguous-K bytes.
// ---------------------------------------------------------------------------
__global__ void k_conv(const float* __restrict__ ef,   const float* __restrict__ ctx,
                       const float* __restrict__ Whi,  const float* __restrict__ Wci,
                       const float* __restrict__ Wih0, const float* __restrict__ Whh0,
                       const float* __restrict__ Wih1, const float* __restrict__ Whh1,
                       const float* __restrict__ Wo1,  const float* __restrict__ Wg1,
                       bf16* __restrict__ efb,  bf16* __restrict__ ctxb,
                       bf16* __restrict__ Wit,  u8* __restrict__ Wt0,
                       u8* __restrict__ Wt1,  u8* __restrict__ Wo1t,
                       u8* __restrict__ Wg1t)
{
    size_t tid = (size_t)blockIdx.x * blockDim.x + threadIdx.x;
    size_t gsz = (size_t)gridDim.x * blockDim.x;
    for (size_t i = tid; i < (size_t)Bsz * Dsz; i += gsz) {
        efb[i]  = __float2bfloat16(ef[i]);
        ctxb[i] = __float2bfloat16(ctx[i]);
    }
    for (size_t i = tid; i < 2048ull * 512 / 4; i += gsz) {   // Wt0[n][k] = Whh0[k][n]
        int n = i >> 7, k = (i & 127) * 4;
        int lo = __builtin_amdgcn_cvt_pk_fp8_f32(Whh0[(size_t)(k+0)*2048+n], Whh0[(size_t)(k+1)*2048+n], 0, false);
        int pk = __builtin_amdgcn_cvt_pk_fp8_f32(Whh0[(size_t)(k+2)*2048+n], Whh0[(size_t)(k+3)*2048+n], lo, true);
        *(int*)(Wt0 + (size_t)n * 512 + k) = pk;
    }
    for (size_t i = tid; i < 2048ull * 1024 / 4; i += gsz) {  // Wt1[n][k] = [Wih1;Whh1][k][n]
        int n = i >> 8, k = (i & 255) * 4;
        float f0, f1, f2, f3;
        if (k < 512) {
            f0 = Wih1[(size_t)(k+0)*2048+n]; f1 = Wih1[(size_t)(k+1)*2048+n];
            f2 = Wih1[(size_t)(k+2)*2048+n]; f3 = Wih1[(size_t)(k+3)*2048+n];
        } else {
            int kk = k - 512;
            f0 = Whh1[(size_t)(kk+0)*2048+n]; f1 = Whh1[(size_t)(kk+1)*2048+n];
            f2 = Whh1[(size_t)(kk+2)*2048+n]; f3 = Whh1[(size_t)(kk+3)*2048+n];
        }
        int lo = __builtin_amdgcn_cvt_pk_fp8_f32(f0, f1, 0, false);
        int pk = __builtin_amdgcn_cvt_pk_fp8_f32(f2, f3, lo, true);
        *(int*)(Wt1 + (size_t)n * 1024 + k) = pk;
    }
    for (size_t i = tid; i < 32ull * 512 / 4; i += gsz) {     // Wo1t/Wg1t[c][k]
        int c = i >> 7, k = (i & 127) * 4;
        int lo = __builtin_amdgcn_cvt_pk_fp8_f32(Wo1[(size_t)(k+0)*32+c], Wo1[(size_t)(k+1)*32+c], 0, false);
        int pk = __builtin_amdgcn_cvt_pk_fp8_f32(Wo1[(size_t)(k+2)*32+c], Wo1[(size_t)(k+3)*32+c], lo, true);
        *(int*)(Wo1t + (size_t)c * 512 + k) = pk;
        lo = __builtin_amdgcn_cvt_pk_fp8_f32(Wg1[(size_t)(k+0)*32+c], Wg1[(size_t)(k+1)*32+c], 0, false);
        pk = __builtin_amdgcn_cvt_pk_fp8_f32(Wg1[(size_t)(k+2)*32+c], Wg1[(size_t)(k+3)*32+c], lo, true);
        *(int*)(Wg1t + (size_t)c * 512 + k) = pk;
    }
    for (size_t i = tid; i < 4096ull * 256; i += gsz) {       // Wit[n][k] bf16
        size_t n = i >> 8, k = i & 255;
        float v = (n < 1024) ? Whi[k * 1024 + n]
                : (n < 2048) ? Wci[k * 1024 + (n - 1024)]
                             : Wih0[(1 + k) * 2048 + (n - 2048)];
        Wit[i] = __float2bfloat16(v);
    }
}

// ---------------------------------------------------------------------------
// Init GEMM (bf16): [h_init | c_init | ctx_gates]; h stored fp8, c f32,
// ctx_gates bf16 [b][j][4 gates].
// ---------------------------------------------------------------------------
__global__ void __launch_bounds__(256)
k_init(const bf16* __restrict__ efb, const bf16* __restrict__ ctxb,
       const bf16* __restrict__ Wit,
       const float* __restrict__ bh,  const float* __restrict__ bc,
       const float* __restrict__ bi0, const float* __restrict__ bh0,
       u8* __restrict__ h0, u8* __restrict__ h1,
       float* __restrict__ c0, float* __restrict__ c1,
       bf16* __restrict__ ctxg)
{
    const int t = threadIdx.x, lane = t & 63, w = t >> 6;
    const int wr = w >> 1, wc = w & 1;
    const int lq = lane >> 4, ln = lane & 15;
    const int m0 = blockIdx.x * 128, n0 = blockIdx.y * 64;
    const bf16* A = (n0 < 2048) ? efb : ctxb;

    f32x4 zero = {0.f, 0.f, 0.f, 0.f};
    f32x4 acc[4][2];
#pragma unroll
    for (int r = 0; r < 4; ++r)
#pragma unroll
        for (int c = 0; c < 2; ++c) acc[r][c] = zero;

    for (int k0 = 0; k0 < 256; k0 += 32) {
        short8 af[4];
#pragma unroll
        for (int r = 0; r < 4; ++r)
            af[r] = *(const short8*)(A + (size_t)(m0 + wr * 64 + r * 16 + ln) * 256 + k0 + lq * 8);
#pragma unroll
        for (int c = 0; c < 2; ++c) {
            short8 bv = *(const short8*)(Wit + (size_t)(n0 + wc * 32 + c * 16 + ln) * 256 + k0 + lq * 8);
#pragma unroll
            for (int r = 0; r < 4; ++r)
                acc[r][c] = __builtin_amdgcn_mfma_f32_16x16x32_bf16(af[r], bv, acc[r][c], 0, 0, 0);
        }
    }
#pragma unroll
    for (int r = 0; r < 4; ++r)
#pragma unroll
        for (int c = 0; c < 2; ++c)
#pragma unroll
            for (int e = 0; e < 4; ++e) {
                int b = m0 + wr * 64 + r * 16 + lq * 4 + e;
                int n = n0 + wc * 32 + c * 16 + ln;
                float v = acc[r][c][e];
                if (n < 1024) {
                    v += bh[n];
                    if (n < 512) h0[(size_t)b * 512 + n]       = f2fp8(v);
                    else         h1[(size_t)b * 512 + n - 512] = f2fp8(v);
                } else if (n < 2048) {
                    int m = n - 1024; v += bc[m];
                    if (m < 512) c0[(size_t)b * 512 + m]       = v;
                    else         c1[(size_t)b * 512 + m - 512] = v;
                } else {
                    int j = n - 2048;
                    ctxg[(size_t)b * 2048 + (j & 511) * 4 + (j >> 9)] =
                        __float2bfloat16(v + bi0[j] + bh0[j]);
                }
            }
}

// ---------------------------------------------------------------------------
// intent head (fp8 MFMA): 128 rows/WG, writes strided out column + iws.
// ---------------------------------------------------------------------------
__global__ void __launch_bounds__(256)
k_intent(const u8* __restrict__ h, const u8* __restrict__ W1t,
         const float* __restrict__ bias1, const float* __restrict__ W2,
         const float* __restrict__ bias2,
         float* __restrict__ outp, int ostride, float* __restrict__ iws)
{
    const int t = threadIdx.x, lane = t & 63, w = t >> 6;
    const int lq = lane >> 4, ln = lane & 15;
    const int m0 = blockIdx.x * 128;
    f32x4 zero = {0.f, 0.f, 0.f, 0.f};
    f32x4 acc[2][2];
#pragma unroll
    for (int r = 0; r < 2; ++r)
#pragma unroll
        for (int c = 0; c < 2; ++c) acc[r][c] = zero;

#pragma unroll
    for (int k0 = 0; k0 < 512; k0 += 32) {
        long av[2], bv[2];
#pragma unroll
        for (int r = 0; r < 2; ++r)
            av[r] = *(const long*)(h + (size_t)(m0 + w * 32 + r * 16 + ln) * 512 + k0 + lq * 8);
#pragma unroll
        for (int c = 0; c < 2; ++c)
            bv[c] = *(const long*)(W1t + (size_t)(c * 16 + ln) * 512 + k0 + lq * 8);
#pragma unroll
        for (int r = 0; r < 2; ++r)
#pragma unroll
            for (int c = 0; c < 2; ++c)
                acc[r][c] = __builtin_amdgcn_mfma_f32_16x16x32_fp8_fp8(av[r], bv[c], acc[r][c], 0, 0, 0);
    }
#pragma unroll
    for (int r = 0; r < 2; ++r)
#pragma unroll
        for (int e = 0; e < 4; ++e) {
            float v = 0.f;
#pragma unroll
            for (int c = 0; c < 2; ++c) {
                int col = c * 16 + ln;
                v += fmaxf(acc[r][c][e] + bias1[col], 0.f) * W2[col];
            }
            v += __shfl_xor(v, 1);
            v += __shfl_xor(v, 2);
            v += __shfl_xor(v, 4);
            v += __shfl_xor(v, 8);
            int row = w * 32 + r * 16 + lq * 4 + e;
            if (ln == 0) {
                float p = sigf(v + bias2[0]);
                outp[(size_t)(m0 + row) * ostride] = p;
                if (iws) iws[m0 + row] = p;
            }
        }
}

// ---------------------------------------------------------------------------
// Staging (fp8, BK=64): A 256 rows x 64B (16 KB) + B 128 brows x 64B (8 KB)
// into one 24 KB ring buffer. 16B chunks, swizzle kc = slot ^ (row&3) applied
// on the GLOBAL side (LDS stays linear). 512 threads: 2 A + 1 B chunk each.
// ---------------------------------------------------------------------------
template <int L0>
__device__ __forceinline__ void stage(const u8* __restrict__ hA, const u8* __restrict__ hB,
                                      const u8* __restrict__ Wt,
                                      int m0, int j0, int k0, char* buf, int t)
{
    constexpr int KW = L0 ? 512 : 1024;
#pragma unroll
    for (int i = 0; i < 2; ++i) {
        int f = i * 512 + t;
        int row = f >> 2, slot = f & 3;
        int kk = k0 + ((slot ^ (row & 3)) << 4);
        const u8* src;
        if (L0) src = hA + (size_t)(m0 + row) * Hsz + kk;
        else    src = (kk < 512) ? hA + (size_t)(m0 + row) * Hsz + kk
                                 : hB + (size_t)(m0 + row) * Hsz + (kk - 512);
        gload16(src, buf + (size_t)f * 16);
    }
    {
        int f = t;
        int brow = f >> 2, slot = f & 3;               // brow = g*32 + n
        int kc = slot ^ (brow & 3);
        gload16(Wt + (size_t)((brow >> 5) * 512 + j0 + (brow & 31)) * KW + k0 + kc * 16,
                buf + 16384 + (size_t)f * 16);
    }
}

// one BK=64 tile of fp8 MFMA per wave: 2 k-halves x 4 gates x 4 row-frags
__device__ __forceinline__ void mfma_tile(const char* buf,
                                          int wr, int wc, int lq, int ln,
                                          f32x4 (&acc)[4][4])
{
#pragma unroll
    for (int kk2 = 0; kk2 < 2; ++kk2) {
        int kc = kk2 * 2 + (lq >> 1), sub = (lq & 1) * 8;
        long af[4], bfr[4];
#pragma unroll
        for (int r = 0; r < 4; ++r) {
            int row = wr * 64 + r * 16 + ln;
            int slot = kc ^ (row & 3);
            af[r] = *(const long*)(buf + (size_t)row * 64 + slot * 16 + sub);
        }
#pragma unroll
        for (int g = 0; g < 4; ++g) {
            int brow = g * 32 + wc * 16 + ln;
            int slot = kc ^ (brow & 3);
            bfr[g] = *(const long*)(buf + 16384 + (size_t)brow * 64 + slot * 16 + sub);
        }
#pragma unroll
        for (int g = 0; g < 4; ++g)
#pragma unroll
            for (int r = 0; r < 4; ++r)
                acc[g][r] = __builtin_amdgcn_mfma_f32_16x16x32_fp8_fp8(af[r], bfr[g], acc[g][r], 0, 0, 0);
    }
}

#define WAIT_VM(N) asm volatile("s_waitcnt vmcnt(" #N ")" ::: "memory")

// ---------------------------------------------------------------------------
// Fused gates GEMM (fp8) + LSTM cell. 256 rows x 32 gate-cols x 4 gates per
// WG (512 thr, 8 waves: wr=w>>1 row-quarter, wc=w&1 col-half). Grid 256 =
// 16 mblk x 16 jblk (all CUs). Ring-4 x 24 KB LDS, depth-3, counted vmcnt.
// ---------------------------------------------------------------------------
template <int L0>
__global__ void __launch_bounds__(512)
k_gates(const u8* __restrict__ hA, const u8* __restrict__ hB,
        const u8* __restrict__ Wt,
        const bf16* __restrict__ ctxg, const float* __restrict__ intent_src,
        const float* __restrict__ w0row,
        const float* __restrict__ b1, const float* __restrict__ b2,
        float* __restrict__ cbuf, u8* __restrict__ hout)
{
    constexpr int KW = L0 ? 512 : 1024;
    constexpr int NT = KW / 64;
    __shared__ __align__(16) char lds[98304];          // 4 ring buffers x 24 KB

    const int t = threadIdx.x, lane = t & 63, w = t >> 6;
    const int wr = w >> 1, wc = w & 1, lq = lane >> 4, ln = lane & 15;
    const int bid = blockIdx.x;
    const int xcd = bid & 7, rem = bid >> 3;
    const int mblk = xcd * 2 + (rem & 1), jblk = rem >> 1;   // mblk-major per XCD
    const int m0 = mblk * 256, j0 = jblk * 32;

    // prologue: 3 stage tiles in flight (9 loads/thread)
    stage<L0>(hA, hB, Wt, m0, j0, 0,   lds,          t);
    stage<L0>(hA, hB, Wt, m0, j0, 64,  lds + 24576,  t);
    stage<L0>(hA, hB, Wt, m0, j0, 128, lds + 49152,  t);

    f32x4 zero = {0.f, 0.f, 0.f, 0.f};
    f32x4 acc[4][4];
#pragma unroll
    for (int g = 0; g < 4; ++g)
#pragma unroll
        for (int r = 0; r < 4; ++r) acc[g][r] = zero;

#pragma unroll 4
    for (int kt = 0; kt < NT - 3; ++kt) {
        WAIT_VM(6);
        __builtin_amdgcn_s_barrier();
        mfma_tile(lds + (size_t)(kt & 3) * 24576, wr, wc, lq, ln, acc);
        stage<L0>(hA, hB, Wt, m0, j0, (kt + 3) * 64, lds + (size_t)((kt + 3) & 3) * 24576, t);
    }
    WAIT_VM(6);
    __builtin_amdgcn_s_barrier();
    mfma_tile(lds + (size_t)((NT - 3) & 3) * 24576, wr, wc, lq, ln, acc);
    WAIT_VM(3);
    __builtin_amdgcn_s_barrier();
    mfma_tile(lds + (size_t)((NT - 2) & 3) * 24576, wr, wc, lq, ln, acc);
    WAIT_VM(0);
    __builtin_amdgcn_s_barrier();
    mfma_tile(lds + (size_t)((NT - 1) & 3) * 24576, wr, wc, lq, ln, acc);

    // ---- fused LSTM cell epilogue. C/D frag: col=lane&15, row=(lane>>4)*4+reg
    const int jl = j0 + wc * 16 + ln;
    float addc[4];
#pragma unroll
    for (int g = 0; g < 4; ++g)
        addc[g] = L0 ? w0row[g * 512 + jl] : (b1[g * 512 + jl] + b2[g * 512 + jl]);

#pragma unroll
    for (int r = 0; r < 4; ++r)
#pragma unroll
        for (int e = 0; e < 4; ++e) {
            int b = m0 + wr * 64 + r * 16 + lq * 4 + e;
            float pre[4];
#pragma unroll
            for (int g = 0; g < 4; ++g) pre[g] = acc[g][r][e];
            if (L0) {
                float it = intent_src[b];
                us4 cg = *(const us4*)((const unsigned short*)ctxg + (size_t)b * 2048 + jl * 4);
#pragma unroll
                for (int g = 0; g < 4; ++g) pre[g] += b2f(cg[g]) + it * addc[g];
            } else {
#pragma unroll
                for (int g = 0; g < 4; ++g) pre[g] += addc[g];
            }
            float ig = sigf(pre[0]), fg = sigf(pre[1]);
            float gg = tanhft(pre[2]), og = sigf(pre[3]);
            size_t idxb = (size_t)b * Hsz + jl;
            float cn = fg * cbuf[idxb] + ig * gg;
            cbuf[idxb] = cn;
            hout[idxb] = f2fp8(og * tanhft(cn));
        }
}

// ---------------------------------------------------------------------------
extern "C" void kernel_launch(void* const* d_in, const int* in_sizes, int n_in,
                              void* d_out, int out_size, void* d_ws, size_t ws_size,
                              hipStream_t stream)
{
    const float* ef   = (const float*)d_in[0];
    const float* ctx  = (const float*)d_in[1];
    const float* ii   = (const float*)d_in[2];
    const float* Whi  = (const float*)d_in[3];
    const float* bh   = (const float*)d_in[4];
    const float* Wci  = (const float*)d_in[5];
    const float* bc   = (const float*)d_in[6];
    const float* Wih0 = (const float*)d_in[7];
    const float* Whh0 = (const float*)d_in[8];
    const float* bi0  = (const float*)d_in[9];
    const float* bh0  = (const float*)d_in[10];
    const float* Wih1 = (const float*)d_in[11];
    const float* Whh1 = (const float*)d_in[12];
    const float* bi1  = (const float*)d_in[13];
    const float* bh1  = (const float*)d_in[14];
    const float* Wo1  = (const float*)d_in[15];
    const float* bo1  = (const float*)d_in[16];
    const float* Wo2  = (const float*)d_in[17];
    const float* bo2  = (const float*)d_in[18];
    const float* Wg1  = (const float*)d_in[19];
    const float* bg1  = (const float*)d_in[20];
    const float* Wg2  = (const float*)d_in[21];
    const float* bg2  = (const float*)d_in[22];
    float* out = (float*)d_out;

    char* ws = (char*)d_ws;
    size_t off = 0;
    auto take = [&](size_t bytes) -> char* {
        char* pp = ws + off;
        off += (bytes + 255) & ~(size_t)255;
        return pp;
    };
    u8*  Wt0     = (u8*)take(2048ull * 512);
    u8*  Wt1     = (u8*)take(2048ull * 1024);
    u8*  Wo1t    = (u8*)take(32ull * 512);
    u8*  Wg1t    = (u8*)take(32ull * 512);
    bf16* Wit    = (bf16*)take(4096ull * 256 * 2);
    bf16* efb    = (bf16*)take((size_t)Bsz * Dsz * 2);
    bf16* ctxb   = (bf16*)take((size_t)Bsz * Dsz * 2);
    u8*  h0x     = (u8*)take((size_t)Bsz * Hsz);
    u8*  h0y     = (u8*)take((size_t)Bsz * Hsz);
    u8*  h1x     = (u8*)take((size_t)Bsz * Hsz);
    u8*  h1y     = (u8*)take((size_t)Bsz * Hsz);
    float* c0    = (float*)take((size_t)Bsz * Hsz * 4);
    float* c1    = (float*)take((size_t)Bsz * Hsz * 4);
    bf16* ctxg   = (bf16*)take((size_t)Bsz * 2048 * 2);
    float* iws   = (float*)take((size_t)Bsz * 4);
    (void)ws_size; (void)in_sizes; (void)n_in; (void)out_size;

    k_conv<<<2048, 256, 0, stream>>>(ef, ctx, Whi, Wci, Wih0, Whh0, Wih1, Whh1, Wo1, Wg1,
                                     efb, ctxb, Wit, Wt0, Wt1, Wo1t, Wg1t);
    k_init<<<dim3(32, 64), 256, 0, stream>>>(efb, ctxb, Wit, bh, bc, bi0, bh0,
                                             h0x, h1x, c0, c1, ctxg);

    for (int s = 0; s < Tsz; ++s) {
        int p = s & 1;
        const u8* h0in  = p ? h0y : h0x;
        u8*       h0out = p ? h0x : h0y;
        const u8* h1in  = p ? h1y : h1x;
        u8*       h1out = p ? h1x : h1y;
        const float* isrc = (s == 0) ? ii : iws;
        k_gates<1><<<256, 512, 0, stream>>>(
            h0in, nullptr, Wt0, ctxg, isrc, Wih0, nullptr, nullptr, c0, h0out);
        k_gates<0><<<256, 512, 0, stream>>>(
            h0out, h1in, Wt1, nullptr, nullptr, nullptr, bi1, bh1, c1, h1out);
        k_intent<<<32, 256, 0, stream>>>(h1out, Wo1t, bo1, Wo2, bo2, out + s, Tsz, iws);
    }
    // final h1 = h1y (s=44 even); global head
    k_intent<<<32, 256, 0, stream>>>(h1y, Wg1t, bg1, Wg2, bg2,
                                     out + (size_t)Bsz * Tsz, 1, nullptr);
}